// Round 17
// baseline (345.155 us; speedup 1.0000x reference)
//
#include <hip/hip_runtime.h>
#include <math.h>

typedef unsigned long long u64;
typedef unsigned int u32;
typedef unsigned char u8;
typedef __attribute__((ext_vector_type(2))) unsigned long long u64x2;
typedef __attribute__((ext_vector_type(4))) int i32x4;

#define NB 8192
#define NS 4096

// ---- ws layout ----
static const size_t OFF_CNT = 0;                            // pcnt[2048] u64
static const size_t OFF_P3  = 16384;                        // p3[2048] double
static const size_t OFF_M8  = 32768;                        // mask8 [8192][4096] i8
static const size_t OFF_BT  = OFF_M8 + (size_t)NB * NS;     // Bt [4096][4096] i8
static const size_t WS_NEED = OFF_BT + (size_t)NS * NS;     // ~48 MB (proven available)
static const size_t OFF_MB  = 32768;                        // popcount fallback layout
static const size_t OFF_WB  = OFF_MB + (size_t)64 * NB * 8;

__device__ __forceinline__ void gload_lds16(const void* g, void* l) {
    __builtin_amdgcn_global_load_lds(
        (const __attribute__((address_space(1))) unsigned int*)g,
        (__attribute__((address_space(3))) unsigned int*)l, 16, 0, 0);
}

// ================= i8-MFMA path =================

// K12: fused prep. g<2048: mask8+pcnt over y. g>=2048: Bt transpose of W.
__global__ __launch_bounds__(256) void k12_prep(
    const float* __restrict__ y, const float* __restrict__ W,
    u32* __restrict__ m8, u32* __restrict__ bt, u64* __restrict__ pcnt)
{
    const int g = blockIdx.x;
    const int t = threadIdx.x;
    if (g < 2048) {
        __shared__ unsigned rc[4];
        const float4* y4 = (const float4*)y;
        size_t base = (size_t)g * 4096 + t;   // float4 index; 16 per thread
        unsigned lcnt = 0;
        #pragma unroll 4
        for (int k = 0; k < 16; ++k) {
            float4 v = y4[base + (size_t)k * 256];
            unsigned b0 = v.x != 0.0f, b1 = v.y != 0.0f, b2 = v.z != 0.0f, b3 = v.w != 0.0f;
            lcnt += b0 + b1 + b2 + b3;
            m8[base + (size_t)k * 256] = b0 | (b1 << 8) | (b2 << 16) | (b3 << 24);
        }
        for (int off = 32; off; off >>= 1) lcnt += __shfl_down(lcnt, off, 64);
        if ((t & 63) == 0) rc[t >> 6] = lcnt;
        __syncthreads();
        if (t == 0) pcnt[g] = (u64)rc[0] + rc[1] + rc[2] + rc[3];
    } else {
        __shared__ float tile[64][65];
        const int gg = g - 2048;
        const int j0 = (gg & 63) * 64, i0 = (gg >> 6) * 64;
        #pragma unroll
        for (int k = 0; k < 16; ++k) {
            int lin = t + (k << 8);
            int r = lin >> 6, c = lin & 63;
            tile[r][c] = W[(size_t)(i0 + r) * NS + (j0 + c)];
        }
        __syncthreads();
        const int jj = t >> 2, ck = t & 3;
        u32 wd[4];
        #pragma unroll
        for (int gq = 0; gq < 4; ++gq) {
            u32 u = 0;
            #pragma unroll
            for (int bb = 0; bb < 4; ++bb)
                u |= (tile[ck * 16 + gq * 4 + bb][jj] != 0.0f ? 1u : 0u) << (8 * bb);
            wd[gq] = u;
        }
        uint4 out = make_uint4(wd[0], wd[1], wd[2], wd[3]);
        *(uint4*)&bt[(((size_t)(j0 + jj) << 12) + (size_t)(i0 + ck * 16)) >> 2] = out;
    }
}

// K3f: 128x128 i8 GEMM; B staged in LDS (R10-verified swizzle+dbuf schedule),
// A fragments read DIRECT FROM GLOBAL (L2/L3-resident m8; conflict-free, no
// swizzle) with a one-iter register prefetch aN[4]. Halves LDS traffic/K-step
// (48KB -> 24KB) and LDS footprint (32KB -> 16KB).
__global__ __launch_bounds__(256) void k3f_mfma(
    const float* __restrict__ y, const float* __restrict__ yhat,
    const u8* __restrict__ m8, const u8* __restrict__ bt,
    double* __restrict__ p3)
{
    __shared__ alignas(16) u8 lds[2][8192];   // B only: [buf][128 rows][64B]
    const int b0 = blockIdx.x << 7;    // 64 row tiles
    const int j0 = blockIdx.y << 7;    // 32 col tiles
    const int t = threadIdx.x, l = t & 63, wv = t >> 6;
    const int wr = wv >> 1, wc = wv & 1;

    // B DMA (R10): thread t owns LDS slot (row4=t>>2, pos=t&3); fetches global
    // chunk pos ^ f(row4), f(r) = (r>>1)&3 (verified 0-conflict).
    const int row4 = t >> 2, pos = t & 3;
    const int chunk = pos ^ ((row4 >> 1) & 3);
    const u8* srcB = bt + ((size_t)(j0 + row4) << 12) + ((size_t)chunk << 4);

    // B frag read: slot = (l>>4) ^ f(l&15)
    const int slot = ((l >> 4) ^ ((l >> 1) & 3)) & 3;
    const int fcbase = ((wc << 6) + (l & 15)) * 64 + (slot << 4);

    // A global frag base: lane l covers row b0 + wr*64 + (l&15) (+fr*16),
    // k-bytes (l>>4)*16 (+ks*64). No swizzle needed (global, no banks).
    const u8* srcA = m8 + ((size_t)(b0 + (wr << 6) + (l & 15)) << 12) + ((l >> 4) << 4);

    i32x4 acc[4][4];
    #pragma unroll
    for (int i = 0; i < 4; ++i)
        #pragma unroll
        for (int j = 0; j < 4; ++j) acc[i][j] = (i32x4){0, 0, 0, 0};

    auto stageB = [&](int s, int buf) {
        const u8* sB = srcB + (s << 6);
        u8* dB = &lds[buf][(size_t)wv << 10];   // wave-uniform base
        gload_lds16(sB, dB);
        gload_lds16(sB + ((size_t)64 << 12), dB + 4096);
    };

    i32x4 aN[4];
    auto loadA = [&](int s, i32x4* dst) {
        #pragma unroll
        for (int fr = 0; fr < 4; ++fr)
            dst[fr] = *(const i32x4*)(srcA + ((size_t)fr << 16) + (s << 6));
    };

    stageB(0, 0);
    loadA(0, aN);
    __syncthreads();   // buffer 0 + aN(0) ready (barrier drains vmcnt)

    #pragma unroll 1
    for (int ks = 0; ks < 64; ++ks) {
        const int cb = ks & 1;
        i32x4 aC[4];
        #pragma unroll
        for (int f = 0; f < 4; ++f) aC[f] = aN[f];
        if (ks < 63) { stageB(ks + 1, cb ^ 1); loadA(ks + 1, aN); }  // async
        const u8* L = lds[cb];
        i32x4 b[4];
        #pragma unroll
        for (int f = 0; f < 4; ++f) b[f] = *(const i32x4*)&L[fcbase + f * 1024];
        #pragma unroll
        for (int fr = 0; fr < 4; ++fr)
            #pragma unroll
            for (int fc = 0; fc < 4; ++fc)
                acc[fr][fc] = __builtin_amdgcn_mfma_i32_16x16x64_i8(
                    aC[fr], b[fc], acc[fr][fc], 0, 0, 0);
        __syncthreads();   // reads done; next buffer DMA + aN drained
    }

    // epilogue: C/D map col=l&15, row=(l>>4)*4+q (R10-verified)
    float part = 0.0f;
    const int col = j0 + (wc << 6) + (l & 15);
    #pragma unroll
    for (int fr = 0; fr < 4; ++fr)
        #pragma unroll
        for (int q = 0; q < 4; ++q) {
            size_t rbase = ((size_t)(b0 + (wr << 6) + (fr << 4) + ((l >> 4) << 2) + q) << 12) + col;
            #pragma unroll
            for (int fc = 0; fc < 4; ++fc) {
                float yv = y[rbase + (fc << 4)];
                float hv = yhat[rbase + (fc << 4)];
                float e = yv - hv;
                float wgt = 0.1f * (float)acc[fr][fc][q] + (yv != 0.0f ? 1.0f : 0.0f);
                part = fmaf(e * e, wgt, part);
            }
        }

    for (int off = 32; off; off >>= 1) part += __shfl_down(part, off, 64);
    float* red = (float*)lds;
    __syncthreads();
    if ((t & 63) == 0) red[t >> 6] = part;
    __syncthreads();
    if (t == 0)
        p3[(size_t)blockIdx.y * gridDim.x + blockIdx.x] =
            (double)red[0] + (double)red[1] + (double)red[2] + (double)red[3];
}

// ================= popcount fallback path (R8, passing) =================

__global__ __launch_bounds__(256) void k1_pack_mask(
    const float* __restrict__ y, u64* __restrict__ mbT, u64* __restrict__ pcnt)
{
    __shared__ unsigned rc[4];
    const unsigned t = threadIdx.x;
    const unsigned lane = t & 63;
    const float4* y4 = (const float4*)y;
    u64 qi = (u64)blockIdx.x * 256 + t;
    const u64 stride = (u64)2048 * 256;
    unsigned lcnt = 0;
    #pragma unroll 4
    for (int it = 0; it < 16; ++it, qi += stride) {
        float4 v = y4[qi];
        u64 b0 = __ballot(v.x != 0.0f);
        u64 b1 = __ballot(v.y != 0.0f);
        u64 b2 = __ballot(v.z != 0.0f);
        u64 b3 = __ballot(v.w != 0.0f);
        lcnt += (v.x != 0.0f) + (v.y != 0.0f) + (v.z != 0.0f) + (v.w != 0.0f);
        if (lane < 4) {
            unsigned sh = lane << 4;
            u64 word = ((b0 >> sh) & 0xFFFFull)
                     | (((b1 >> sh) & 0xFFFFull) << 16)
                     | (((b2 >> sh) & 0xFFFFull) << 32)
                     | (((b3 >> sh) & 0xFFFFull) << 48);
            u64 gw = ((qi - lane) >> 4) + lane;
            mbT[((gw & 63) << 13) + (gw >> 6)] = word;
        }
    }
    for (int off = 32; off; off >>= 1) lcnt += __shfl_down(lcnt, off, 64);
    if ((t & 63) == 0) rc[t >> 6] = lcnt;
    __syncthreads();
    if (t == 0) pcnt[blockIdx.x] = (u64)rc[0] + rc[1] + rc[2] + rc[3];
}

__global__ __launch_bounds__(256) void k2_pack_w(
    const float* __restrict__ W, u64* __restrict__ wbT)
{
    __shared__ float tile[64][65];
    const int j0 = blockIdx.x * 64;
    const int w  = blockIdx.y;
    const int i0 = w * 64;
    const int t = threadIdx.x;
    #pragma unroll
    for (int k = 0; k < 16; ++k) {
        int lin = t + (k << 8);
        int r = lin >> 6, c = lin & 63;
        tile[r][c] = W[(size_t)(i0 + r) * NS + (j0 + c)];
    }
    __syncthreads();
    const int lane = t & 63;
    const int wvv = t >> 6;
    const int pr = ((lane & 15) << 2) + (lane >> 4);
    for (int jj = wvv; jj < 64; jj += 4) {
        u64 bal = __ballot(tile[pr][jj] != 0.0f);
        if (lane == 0) wbT[((size_t)w << 12) + (j0 + jj)] = bal;
    }
}

__global__ __launch_bounds__(256) void k3_main(
    const float* __restrict__ y, const float* __restrict__ yhat,
    const u64* __restrict__ mbT, const u64* __restrict__ wbT,
    double* __restrict__ p3)
{
    __shared__ alignas(16) u64 mT[16 * 128];
    __shared__ alignas(16) u64 wT[16 * 128];
    const int b0 = blockIdx.x << 7;
    const int j0 = blockIdx.y << 7;
    const int t  = threadIdx.x;
    const int r0 = (t >> 4) << 3;
    const int cj = t & 15;
    const unsigned sx = ((unsigned)cj >> 2) << 4;

    unsigned cnt[8][8];
    #pragma unroll
    for (int a = 0; a < 8; ++a)
        #pragma unroll
        for (int b = 0; b < 8; ++b) cnt[a][b] = 0;

    char* mB = (char*)mT;
    char* wB = (char*)wT;

    #pragma unroll 1
    for (int s = 0; s < 4; ++s) {
        u64x2 gm[4], gq[4];
        #pragma unroll
        for (int k = 0; k < 4; ++k) {
            int lin = t + (k << 8);
            int wl = (s << 4) + (lin >> 6), c2 = lin & 63;
            gm[k] = *(const u64x2*)&mbT[((size_t)wl << 13) + b0 + 2 * c2];
            gq[k] = *(const u64x2*)&wbT[((size_t)wl << 12) + j0 + 2 * c2];
        }
        __syncthreads();
        #pragma unroll
        for (int k = 0; k < 4; ++k) {
            int lin = t + (k << 8);
            int wl = lin >> 6, c2 = lin & 63;
            int p = c2 ^ ((c2 >> 4) & 3);
            *(u64x2*)(mB + (wl << 10) + (c2 << 4)) = gm[k];
            *(u64x2*)(wB + (wl << 10) + (p << 4)) = gq[k];
        }
        __syncthreads();

        unsigned mo = (unsigned)(r0 << 3);
        unsigned qs = (unsigned)(cj << 6) + sx;
        #pragma unroll 2
        for (int w = 0; w < 16; ++w) {
            unsigned ml[16], ql[16];
            #pragma unroll
            for (int k = 0; k < 4; ++k) {
                uint4 a = *(const uint4*)(mB + mo + (k << 4));
                ml[4 * k + 0] = a.x; ml[4 * k + 1] = a.y;
                ml[4 * k + 2] = a.z; ml[4 * k + 3] = a.w;
                uint4 b = *(const uint4*)(wB + (qs ^ (unsigned)(k << 4)));
                ql[4 * k + 0] = b.x; ql[4 * k + 1] = b.y;
                ql[4 * k + 2] = b.z; ql[4 * k + 3] = b.w;
            }
            #pragma unroll
            for (int aa = 0; aa < 8; ++aa)
                #pragma unroll
                for (int bb = 0; bb < 8; ++bb) {
                    unsigned x0 = ml[2 * aa] & ql[2 * bb];
                    unsigned x1 = ml[2 * aa + 1] & ql[2 * bb + 1];
                    asm("v_bcnt_u32_b32 %0, %1, %0" : "+v"(cnt[aa][bb]) : "v"(x0));
                    asm("v_bcnt_u32_b32 %0, %1, %0" : "+v"(cnt[aa][bb]) : "v"(x1));
                }
            mo += 1024; qs += 1024;
        }
    }

    float part = 0.0f;
    const int c0 = cj << 3;
    #pragma unroll
    for (int aa = 0; aa < 8; ++aa) {
        size_t off = ((size_t)(b0 + r0 + aa) << 12) + (size_t)(j0 + c0);
        float ys[8], hs[8];
        *(float4*)&ys[0] = *(const float4*)(y + off);
        *(float4*)&ys[4] = *(const float4*)(y + off + 4);
        *(float4*)&hs[0] = *(const float4*)(yhat + off);
        *(float4*)&hs[4] = *(const float4*)(yhat + off + 4);
        #pragma unroll
        for (int bb = 0; bb < 8; ++bb) {
            float e = ys[bb] - hs[bb];
            float wgt = 0.1f * (float)cnt[aa][bb] + (ys[bb] != 0.0f ? 1.0f : 0.0f);
            part = fmaf(e * e, wgt, part);
        }
    }

    for (int off = 32; off; off >>= 1) part += __shfl_down(part, off, 64);
    float* red = (float*)mT;
    __syncthreads();
    if ((t & 63) == 0) red[t >> 6] = part;
    __syncthreads();
    if (t == 0)
        p3[(size_t)blockIdx.y * gridDim.x + blockIdx.x] =
            (double)red[0] + (double)red[1] + (double)red[2] + (double)red[3];
}

// ---------------- K4: final reduce + sqrt ----------------
__global__ __launch_bounds__(256) void k4_final(
    const u64* __restrict__ pcnt, const double* __restrict__ p3, float* __restrict__ out)
{
    __shared__ double rs[4];
    __shared__ u64 rcc[4];
    double s3 = 0.0;
    u64 c = 0;
    for (int i = threadIdx.x; i < 2048; i += 256) { s3 += p3[i]; c += pcnt[i]; }
    for (int off = 32; off; off >>= 1) {
        s3 += __shfl_down(s3, off, 64);
        c  += __shfl_down(c, off, 64);
    }
    int wv = threadIdx.x >> 6;
    if ((threadIdx.x & 63) == 0) { rs[wv] = s3; rcc[wv] = c; }
    __syncthreads();
    if (threadIdx.x == 0) {
        double S3 = rs[0] + rs[1] + rs[2] + rs[3];
        double C  = (double)(rcc[0] + rcc[1] + rcc[2] + rcc[3]);
        out[0] = (float)sqrt(S3 / C + 1e-6);
    }
}

extern "C" void kernel_launch(void* const* d_in, const int* in_sizes, int n_in,
                              void* d_out, int out_size, void* d_ws, size_t ws_size,
                              hipStream_t stream) {
    const float* yhat = (const float*)d_in[0];
    const float* y    = (const float*)d_in[1];
    const float* W    = (const float*)d_in[2];
    char* ws = (char*)d_ws;
    u64*    pcnt = (u64*)(ws + OFF_CNT);
    double* p3   = (double*)(ws + OFF_P3);

    if (ws_size >= WS_NEED) {
        u32* m8 = (u32*)(ws + OFF_M8);
        u32* bt = (u32*)(ws + OFF_BT);
        k12_prep<<<dim3(2048 + 4096), dim3(256), 0, stream>>>(y, W, m8, bt, pcnt);
        k3f_mfma<<<dim3(64, 32), dim3(256), 0, stream>>>(
            y, yhat, (const u8*)m8, (const u8*)bt, p3);
        k4_final<<<dim3(1), dim3(256), 0, stream>>>(pcnt, p3, (float*)d_out);
    } else {
        u64* mbT = (u64*)(ws + OFF_MB);
        u64* wbT = (u64*)(ws + OFF_WB);
        k1_pack_mask<<<dim3(2048), dim3(256), 0, stream>>>(y, mbT, pcnt);
        k2_pack_w<<<dim3(64, 64), dim3(256), 0, stream>>>(W, wbT);
        k3_main<<<dim3(64, 32), dim3(256), 0, stream>>>(y, yhat, mbT, wbT, p3);
        k4_final<<<dim3(1), dim3(256), 0, stream>>>(pcnt, p3, (float*)d_out);
    }
}

// Round 18
// 222.624 us; speedup vs baseline: 1.5504x; 1.5504x over previous
//
#include <hip/hip_runtime.h>
#include <math.h>

typedef unsigned long long u64;
typedef unsigned int u32;
typedef unsigned char u8;
typedef __attribute__((ext_vector_type(2))) unsigned long long u64x2;
typedef __attribute__((ext_vector_type(4))) int i32x4;

#define NB 8192
#define NS 4096

// ---- ws layout ----
static const size_t OFF_CNT = 0;                            // pcnt[2048] u64
static const size_t OFF_P3  = 16384;                        // p3[2048] double
static const size_t OFF_M8  = 32768;                        // mask8 [8192][4096] i8
static const size_t OFF_BT  = OFF_M8 + (size_t)NB * NS;     // Bt [4096][4096] i8
static const size_t WS_NEED = OFF_BT + (size_t)NS * NS;     // ~48 MB (proven available)
static const size_t OFF_MB  = 32768;                        // popcount fallback layout
static const size_t OFF_WB  = OFF_MB + (size_t)64 * NB * 8;

__device__ __forceinline__ void gload_lds16(const void* g, void* l) {
    __builtin_amdgcn_global_load_lds(
        (const __attribute__((address_space(1))) unsigned int*)g,
        (__attribute__((address_space(3))) unsigned int*)l, 16, 0, 0);
}

// ================= i8-MFMA path =================

// K12: fused prep (R17-verified). g<2048: mask8+pcnt over y. g>=2048: Bt of W.
__global__ __launch_bounds__(256) void k12_prep(
    const float* __restrict__ y, const float* __restrict__ W,
    u32* __restrict__ m8, u32* __restrict__ bt, u64* __restrict__ pcnt)
{
    const int g = blockIdx.x;
    const int t = threadIdx.x;
    if (g < 2048) {
        __shared__ unsigned rc[4];
        const float4* y4 = (const float4*)y;
        size_t base = (size_t)g * 4096 + t;   // float4 index; 16 per thread
        unsigned lcnt = 0;
        #pragma unroll 4
        for (int k = 0; k < 16; ++k) {
            float4 v = y4[base + (size_t)k * 256];
            unsigned b0 = v.x != 0.0f, b1 = v.y != 0.0f, b2 = v.z != 0.0f, b3 = v.w != 0.0f;
            lcnt += b0 + b1 + b2 + b3;
            m8[base + (size_t)k * 256] = b0 | (b1 << 8) | (b2 << 16) | (b3 << 24);
        }
        for (int off = 32; off; off >>= 1) lcnt += __shfl_down(lcnt, off, 64);
        if ((t & 63) == 0) rc[t >> 6] = lcnt;
        __syncthreads();
        if (t == 0) pcnt[g] = (u64)rc[0] + rc[1] + rc[2] + rc[3];
    } else {
        __shared__ float tile[64][65];
        const int gg = g - 2048;
        const int j0 = (gg & 63) * 64, i0 = (gg >> 6) * 64;
        #pragma unroll
        for (int k = 0; k < 16; ++k) {
            int lin = t + (k << 8);
            int r = lin >> 6, c = lin & 63;
            tile[r][c] = W[(size_t)(i0 + r) * NS + (j0 + c)];
        }
        __syncthreads();
        const int jj = t >> 2, ck = t & 3;
        u32 wd[4];
        #pragma unroll
        for (int gq = 0; gq < 4; ++gq) {
            u32 u = 0;
            #pragma unroll
            for (int bb = 0; bb < 4; ++bb)
                u |= (tile[ck * 16 + gq * 4 + bb][jj] != 0.0f ? 1u : 0u) << (8 * bb);
            wd[gq] = u;
        }
        uint4 out = make_uint4(wd[0], wd[1], wd[2], wd[3]);
        *(uint4*)&bt[(((size_t)(j0 + jj) << 12) + (size_t)(i0 + ck * 16)) >> 2] = out;
    }
}

// K3b (R10-exact, best measured: 186us, MfmaUtil 30%, 0 conflicts):
// 128x128 i8 GEMM, dbuf LDS staged by global_load_lds, swizzle f(r)=(r>>1)&3
// on DMA-source + read side, fused sq-weighted epilogue.
__global__ __launch_bounds__(256) void k3b_mfma(
    const float* __restrict__ y, const float* __restrict__ yhat,
    const u8* __restrict__ m8, const u8* __restrict__ bt,
    double* __restrict__ p3)
{
    __shared__ alignas(16) u8 lds[2][16384];
    const int b0 = blockIdx.x << 7;    // 64 row tiles
    const int j0 = blockIdx.y << 7;    // 32 col tiles
    const int t = threadIdx.x, l = t & 63, wv = t >> 6;
    const int wr = wv >> 1, wc = wv & 1;

    const int row4 = t >> 2, pos = t & 3;
    const int chunk = pos ^ ((row4 >> 1) & 3);
    const u8* srcA = m8 + ((size_t)(b0 + row4) << 12) + ((size_t)chunk << 4);
    const u8* srcB = bt + ((size_t)(j0 + row4) << 12) + ((size_t)chunk << 4);

    const int slot = ((l >> 4) ^ ((l >> 1) & 3)) & 3;
    const int frbase = ((wr << 6) + (l & 15)) * 64 + (slot << 4);
    const int fcbase = 8192 + ((wc << 6) + (l & 15)) * 64 + (slot << 4);

    i32x4 acc[4][4];
    #pragma unroll
    for (int i = 0; i < 4; ++i)
        #pragma unroll
        for (int j = 0; j < 4; ++j) acc[i][j] = (i32x4){0, 0, 0, 0};

    auto stage = [&](int s, int buf) {
        const u8* sA = srcA + (s << 6);
        const u8* sB = srcB + (s << 6);
        u8* dA = &lds[buf][(size_t)wv << 10];
        u8* dB = &lds[buf][8192 + ((size_t)wv << 10)];
        gload_lds16(sA, dA);
        gload_lds16(sA + ((size_t)64 << 12), dA + 4096);
        gload_lds16(sB, dB);
        gload_lds16(sB + ((size_t)64 << 12), dB + 4096);
    };

    stage(0, 0);
    __syncthreads();

    #pragma unroll 1
    for (int ks = 0; ks < 64; ++ks) {
        const int cb = ks & 1;
        if (ks < 63) stage(ks + 1, cb ^ 1);
        const u8* L = lds[cb];
        i32x4 a[4], b[4];
        #pragma unroll
        for (int f = 0; f < 4; ++f) {
            a[f] = *(const i32x4*)&L[frbase + f * 1024];
            b[f] = *(const i32x4*)&L[fcbase + f * 1024];
        }
        #pragma unroll
        for (int fr = 0; fr < 4; ++fr)
            #pragma unroll
            for (int fc = 0; fc < 4; ++fc)
                acc[fr][fc] = __builtin_amdgcn_mfma_i32_16x16x64_i8(
                    a[fr], b[fc], acc[fr][fc], 0, 0, 0);
        __syncthreads();
    }

    // epilogue: C/D map col=l&15, row=(l>>4)*4+q (R10-verified)
    float part = 0.0f;
    const int col = j0 + (wc << 6) + (l & 15);
    #pragma unroll
    for (int fr = 0; fr < 4; ++fr)
        #pragma unroll
        for (int q = 0; q < 4; ++q) {
            size_t rbase = ((size_t)(b0 + (wr << 6) + (fr << 4) + ((l >> 4) << 2) + q) << 12) + col;
            #pragma unroll
            for (int fc = 0; fc < 4; ++fc) {
                float yv = y[rbase + (fc << 4)];
                float hv = yhat[rbase + (fc << 4)];
                float e = yv - hv;
                float wgt = 0.1f * (float)acc[fr][fc][q] + (yv != 0.0f ? 1.0f : 0.0f);
                part = fmaf(e * e, wgt, part);
            }
        }

    for (int off = 32; off; off >>= 1) part += __shfl_down(part, off, 64);
    float* red = (float*)lds;
    __syncthreads();
    if ((t & 63) == 0) red[t >> 6] = part;
    __syncthreads();
    if (t == 0)
        p3[(size_t)blockIdx.y * gridDim.x + blockIdx.x] =
            (double)red[0] + (double)red[1] + (double)red[2] + (double)red[3];
}

// ================= popcount fallback path (R8, passing) =================

__global__ __launch_bounds__(256) void k1_pack_mask(
    const float* __restrict__ y, u64* __restrict__ mbT, u64* __restrict__ pcnt)
{
    __shared__ unsigned rc[4];
    const unsigned t = threadIdx.x;
    const unsigned lane = t & 63;
    const float4* y4 = (const float4*)y;
    u64 qi = (u64)blockIdx.x * 256 + t;
    const u64 stride = (u64)2048 * 256;
    unsigned lcnt = 0;
    #pragma unroll 4
    for (int it = 0; it < 16; ++it, qi += stride) {
        float4 v = y4[qi];
        u64 b0 = __ballot(v.x != 0.0f);
        u64 b1 = __ballot(v.y != 0.0f);
        u64 b2 = __ballot(v.z != 0.0f);
        u64 b3 = __ballot(v.w != 0.0f);
        lcnt += (v.x != 0.0f) + (v.y != 0.0f) + (v.z != 0.0f) + (v.w != 0.0f);
        if (lane < 4) {
            unsigned sh = lane << 4;
            u64 word = ((b0 >> sh) & 0xFFFFull)
                     | (((b1 >> sh) & 0xFFFFull) << 16)
                     | (((b2 >> sh) & 0xFFFFull) << 32)
                     | (((b3 >> sh) & 0xFFFFull) << 48);
            u64 gw = ((qi - lane) >> 4) + lane;
            mbT[((gw & 63) << 13) + (gw >> 6)] = word;
        }
    }
    for (int off = 32; off; off >>= 1) lcnt += __shfl_down(lcnt, off, 64);
    if ((t & 63) == 0) rc[t >> 6] = lcnt;
    __syncthreads();
    if (t == 0) pcnt[blockIdx.x] = (u64)rc[0] + rc[1] + rc[2] + rc[3];
}

__global__ __launch_bounds__(256) void k2_pack_w(
    const float* __restrict__ W, u64* __restrict__ wbT)
{
    __shared__ float tile[64][65];
    const int j0 = blockIdx.x * 64;
    const int w  = blockIdx.y;
    const int i0 = w * 64;
    const int t = threadIdx.x;
    #pragma unroll
    for (int k = 0; k < 16; ++k) {
        int lin = t + (k << 8);
        int r = lin >> 6, c = lin & 63;
        tile[r][c] = W[(size_t)(i0 + r) * NS + (j0 + c)];
    }
    __syncthreads();
    const int lane = t & 63;
    const int wvv = t >> 6;
    const int pr = ((lane & 15) << 2) + (lane >> 4);
    for (int jj = wvv; jj < 64; jj += 4) {
        u64 bal = __ballot(tile[pr][jj] != 0.0f);
        if (lane == 0) wbT[((size_t)w << 12) + (j0 + jj)] = bal;
    }
}

__global__ __launch_bounds__(256) void k3_main(
    const float* __restrict__ y, const float* __restrict__ yhat,
    const u64* __restrict__ mbT, const u64* __restrict__ wbT,
    double* __restrict__ p3)
{
    __shared__ alignas(16) u64 mT[16 * 128];
    __shared__ alignas(16) u64 wT[16 * 128];
    const int b0 = blockIdx.x << 7;
    const int j0 = blockIdx.y << 7;
    const int t  = threadIdx.x;
    const int r0 = (t >> 4) << 3;
    const int cj = t & 15;
    const unsigned sx = ((unsigned)cj >> 2) << 4;

    unsigned cnt[8][8];
    #pragma unroll
    for (int a = 0; a < 8; ++a)
        #pragma unroll
        for (int b = 0; b < 8; ++b) cnt[a][b] = 0;

    char* mB = (char*)mT;
    char* wB = (char*)wT;

    #pragma unroll 1
    for (int s = 0; s < 4; ++s) {
        u64x2 gm[4], gq[4];
        #pragma unroll
        for (int k = 0; k < 4; ++k) {
            int lin = t + (k << 8);
            int wl = (s << 4) + (lin >> 6), c2 = lin & 63;
            gm[k] = *(const u64x2*)&mbT[((size_t)wl << 13) + b0 + 2 * c2];
            gq[k] = *(const u64x2*)&wbT[((size_t)wl << 12) + j0 + 2 * c2];
        }
        __syncthreads();
        #pragma unroll
        for (int k = 0; k < 4; ++k) {
            int lin = t + (k << 8);
            int wl = lin >> 6, c2 = lin & 63;
            int p = c2 ^ ((c2 >> 4) & 3);
            *(u64x2*)(mB + (wl << 10) + (c2 << 4)) = gm[k];
            *(u64x2*)(wB + (wl << 10) + (p << 4)) = gq[k];
        }
        __syncthreads();

        unsigned mo = (unsigned)(r0 << 3);
        unsigned qs = (unsigned)(cj << 6) + sx;
        #pragma unroll 2
        for (int w = 0; w < 16; ++w) {
            unsigned ml[16], ql[16];
            #pragma unroll
            for (int k = 0; k < 4; ++k) {
                uint4 a = *(const uint4*)(mB + mo + (k << 4));
                ml[4 * k + 0] = a.x; ml[4 * k + 1] = a.y;
                ml[4 * k + 2] = a.z; ml[4 * k + 3] = a.w;
                uint4 b = *(const uint4*)(wB + (qs ^ (unsigned)(k << 4)));
                ql[4 * k + 0] = b.x; ql[4 * k + 1] = b.y;
                ql[4 * k + 2] = b.z; ql[4 * k + 3] = b.w;
            }
            #pragma unroll
            for (int aa = 0; aa < 8; ++aa)
                #pragma unroll
                for (int bb = 0; bb < 8; ++bb) {
                    unsigned x0 = ml[2 * aa] & ql[2 * bb];
                    unsigned x1 = ml[2 * aa + 1] & ql[2 * bb + 1];
                    asm("v_bcnt_u32_b32 %0, %1, %0" : "+v"(cnt[aa][bb]) : "v"(x0));
                    asm("v_bcnt_u32_b32 %0, %1, %0" : "+v"(cnt[aa][bb]) : "v"(x1));
                }
            mo += 1024; qs += 1024;
        }
    }

    float part = 0.0f;
    const int c0 = cj << 3;
    #pragma unroll
    for (int aa = 0; aa < 8; ++aa) {
        size_t off = ((size_t)(b0 + r0 + aa) << 12) + (size_t)(j0 + c0);
        float ys[8], hs[8];
        *(float4*)&ys[0] = *(const float4*)(y + off);
        *(float4*)&ys[4] = *(const float4*)(y + off + 4);
        *(float4*)&hs[0] = *(const float4*)(yhat + off);
        *(float4*)&hs[4] = *(const float4*)(yhat + off + 4);
        #pragma unroll
        for (int bb = 0; bb < 8; ++bb) {
            float e = ys[bb] - hs[bb];
            float wgt = 0.1f * (float)cnt[aa][bb] + (ys[bb] != 0.0f ? 1.0f : 0.0f);
            part = fmaf(e * e, wgt, part);
        }
    }

    for (int off = 32; off; off >>= 1) part += __shfl_down(part, off, 64);
    float* red = (float*)mT;
    __syncthreads();
    if ((t & 63) == 0) red[t >> 6] = part;
    __syncthreads();
    if (t == 0)
        p3[(size_t)blockIdx.y * gridDim.x + blockIdx.x] =
            (double)red[0] + (double)red[1] + (double)red[2] + (double)red[3];
}

// ---------------- K4: final reduce + sqrt ----------------
__global__ __launch_bounds__(256) void k4_final(
    const u64* __restrict__ pcnt, const double* __restrict__ p3, float* __restrict__ out)
{
    __shared__ double rs[4];
    __shared__ u64 rcc[4];
    double s3 = 0.0;
    u64 c = 0;
    for (int i = threadIdx.x; i < 2048; i += 256) { s3 += p3[i]; c += pcnt[i]; }
    for (int off = 32; off; off >>= 1) {
        s3 += __shfl_down(s3, off, 64);
        c  += __shfl_down(c, off, 64);
    }
    int wv = threadIdx.x >> 6;
    if ((threadIdx.x & 63) == 0) { rs[wv] = s3; rcc[wv] = c; }
    __syncthreads();
    if (threadIdx.x == 0) {
        double S3 = rs[0] + rs[1] + rs[2] + rs[3];
        double C  = (double)(rcc[0] + rcc[1] + rcc[2] + rcc[3]);
        out[0] = (float)sqrt(S3 / C + 1e-6);
    }
}

extern "C" void kernel_launch(void* const* d_in, const int* in_sizes, int n_in,
                              void* d_out, int out_size, void* d_ws, size_t ws_size,
                              hipStream_t stream) {
    const float* yhat = (const float*)d_in[0];
    const float* y    = (const float*)d_in[1];
    const float* W    = (const float*)d_in[2];
    char* ws = (char*)d_ws;
    u64*    pcnt = (u64*)(ws + OFF_CNT);
    double* p3   = (double*)(ws + OFF_P3);

    if (ws_size >= WS_NEED) {
        u32* m8 = (u32*)(ws + OFF_M8);
        u32* bt = (u32*)(ws + OFF_BT);
        k12_prep<<<dim3(2048 + 4096), dim3(256), 0, stream>>>(y, W, m8, bt, pcnt);
        k3b_mfma<<<dim3(64, 32), dim3(256), 0, stream>>>(
            y, yhat, (const u8*)m8, (const u8*)bt, p3);
        k4_final<<<dim3(1), dim3(256), 0, stream>>>(pcnt, p3, (float*)d_out);
    } else {
        u64* mbT = (u64*)(ws + OFF_MB);
        u64* wbT = (u64*)(ws + OFF_WB);
        k1_pack_mask<<<dim3(2048), dim3(256), 0, stream>>>(y, mbT, pcnt);
        k2_pack_w<<<dim3(64, 64), dim3(256), 0, stream>>>(W, wbT);
        k3_main<<<dim3(64, 32), dim3(256), 0, stream>>>(y, yhat, mbT, wbT, p3);
        k4_final<<<dim3(1), dim3(256), 0, stream>>>(pcnt, p3, (float*)d_out);
    }
}

// Round 19
// 200.178 us; speedup vs baseline: 1.7242x; 1.1121x over previous
//
#include <hip/hip_runtime.h>
#include <math.h>

typedef unsigned long long u64;
typedef unsigned int u32;
typedef unsigned char u8;
typedef __attribute__((ext_vector_type(2))) unsigned long long u64x2;
typedef __attribute__((ext_vector_type(4))) int i32x4;

#define NB 8192
#define NS 4096

// ---- ws layout ----
static const size_t OFF_CNT = 0;                            // pcnt[2048] u64
static const size_t OFF_P3  = 16384;                        // p3[<=2048] double
static const size_t OFF_M8  = 32768;                        // mask8 [8192][4096] i8
static const size_t OFF_BT  = OFF_M8 + (size_t)NB * NS;     // Bt [4096][4096] i8
static const size_t WS_NEED = OFF_BT + (size_t)NS * NS;     // ~48 MB (proven available)
static const size_t OFF_MB  = 32768;                        // popcount fallback layout
static const size_t OFF_WB  = OFF_MB + (size_t)64 * NB * 8;

__device__ __forceinline__ void gload_lds16(const void* g, void* l) {
    __builtin_amdgcn_global_load_lds(
        (const __attribute__((address_space(1))) unsigned int*)g,
        (__attribute__((address_space(3))) unsigned int*)l, 16, 0, 0);
}

// ================= i8-MFMA path =================

// K12: fused prep (R17-verified). g<2048: mask8+pcnt over y. g>=2048: Bt of W.
__global__ __launch_bounds__(256) void k12_prep(
    const float* __restrict__ y, const float* __restrict__ W,
    u32* __restrict__ m8, u32* __restrict__ bt, u64* __restrict__ pcnt)
{
    const int g = blockIdx.x;
    const int t = threadIdx.x;
    if (g < 2048) {
        __shared__ unsigned rc[4];
        const float4* y4 = (const float4*)y;
        size_t base = (size_t)g * 4096 + t;
        unsigned lcnt = 0;
        #pragma unroll 4
        for (int k = 0; k < 16; ++k) {
            float4 v = y4[base + (size_t)k * 256];
            unsigned b0 = v.x != 0.0f, b1 = v.y != 0.0f, b2 = v.z != 0.0f, b3 = v.w != 0.0f;
            lcnt += b0 + b1 + b2 + b3;
            m8[base + (size_t)k * 256] = b0 | (b1 << 8) | (b2 << 16) | (b3 << 24);
        }
        for (int off = 32; off; off >>= 1) lcnt += __shfl_down(lcnt, off, 64);
        if ((t & 63) == 0) rc[t >> 6] = lcnt;
        __syncthreads();
        if (t == 0) pcnt[g] = (u64)rc[0] + rc[1] + rc[2] + rc[3];
    } else {
        __shared__ float tile[64][65];
        const int gg = g - 2048;
        const int j0 = (gg & 63) * 64, i0 = (gg >> 6) * 64;
        #pragma unroll
        for (int k = 0; k < 16; ++k) {
            int lin = t + (k << 8);
            int r = lin >> 6, c = lin & 63;
            tile[r][c] = W[(size_t)(i0 + r) * NS + (j0 + c)];
        }
        __syncthreads();
        const int jj = t >> 2, ck = t & 3;
        u32 wd[4];
        #pragma unroll
        for (int gq = 0; gq < 4; ++gq) {
            u32 u = 0;
            #pragma unroll
            for (int bb = 0; bb < 4; ++bb)
                u |= (tile[ck * 16 + gq * 4 + bb][jj] != 0.0f ? 1u : 0u) << (8 * bb);
            wd[gq] = u;
        }
        uint4 out = make_uint4(wd[0], wd[1], wd[2], wd[3]);
        *(uint4*)&bt[(((size_t)(j0 + jj) << 12) + (size_t)(i0 + ck * 16)) >> 2] = out;
    }
}

// K3g: 256x256 tile, 512 threads / 8 waves (2M x 4N), per-wave 128x64.
// i8 transliteration of the 8-phase template: K-tile = 128 B, dbuf 2x64KB LDS,
// counted vmcnt(8) (2-deep stage pipeline, never drained to 0 in-loop),
// 4 MFMA-phases per K-tile with setprio, swizzle slot^=(row&7) (128B stride)
// applied via pre-swizzled global source + matching read XOR.
__global__ __launch_bounds__(512, 2) void k3g_mfma(
    const float* __restrict__ y, const float* __restrict__ yhat,
    const u8* __restrict__ m8, const u8* __restrict__ bt,
    double* __restrict__ p3)
{
    __shared__ alignas(16) u8 lds[2][65536];   // [buf][ A 32KB (256x128B) | B 32KB ]
    const int b0 = blockIdx.x << 8;    // 32 row tiles (256 rows)
    const int j0 = blockIdx.y << 8;    // 16 col tiles (256 cols)
    const int t = threadIdx.x, l = t & 63, wv = t >> 6;   // 8 waves
    const int wr = wv >> 2, wc = wv & 3;                  // 2M x 4N

    // staging: thread covers (srow = t>>3 in 64-row call group, slot p = t&7);
    // fetches global chunk p ^ (row&7)  [row&7 == srow&7 since group bases %8==0]
    const int srow = t >> 3;
    const int schunk = (t & 7) ^ (srow & 7);
    const u8* sA = m8 + ((size_t)(b0 + srow) << 12) + ((size_t)schunk << 4);
    const u8* sB = bt + ((size_t)(j0 + srow) << 12) + ((size_t)schunk << 4);

    // frag reads: row = base + (l&15), logical chunk q = ks*4 + (l>>4),
    // physical slot = q ^ (l&7)  [base%8==0 -> row&7 == l&7]
    const int rl = l & 15, qh = l >> 4, rx = l & 7;
    const int sb0 = (((0 + qh) ^ rx) << 4);   // ks=0 slot byte
    const int sb1 = (((4 + qh) ^ rx) << 4);   // ks=1 slot byte

    i32x4 acc[8][4];
    #pragma unroll
    for (int i = 0; i < 8; ++i)
        #pragma unroll
        for (int j = 0; j < 4; ++j) acc[i][j] = (i32x4){0, 0, 0, 0};

    // stage K-tile kt2 into buf: 8 gload_lds/thread (A h0,h1 + B h0,h1 x c0,c1)
    auto stage = [&](int kt2, int buf) {
        const size_t ko = (size_t)kt2 << 7;   // 128 B per K-tile
        u8* dst = &lds[buf][0];
        #pragma unroll
        for (int h = 0; h < 2; ++h)
            #pragma unroll
            for (int c = 0; c < 2; ++c) {
                const size_t roff = ((size_t)(h * 128 + c * 64) << 12);
                u8* d = dst + h * 16384 + c * 8192 + (wv << 10);
                gload_lds16(sA + roff + ko, d);
                gload_lds16(sB + roff + ko, d + 32768);
            }
    };

    stage(0, 0);
    stage(1, 1);
    asm volatile("s_waitcnt vmcnt(8)" ::: "memory");   // stage(0) landed
    __builtin_amdgcn_s_barrier();
    asm volatile("" ::: "memory");

    #pragma unroll 1
    for (int kt = 0; kt < 32; ++kt) {
        const u8* L = lds[kt & 1];

        // phase 0 loads B for the whole K-tile (stays live across phases)
        i32x4 b[4][2];
        #pragma unroll
        for (int fc = 0; fc < 4; ++fc) {
            const int cbyte = 32768 + (((wc << 6) + (fc << 4) + rl) << 7);
            b[fc][0] = *(const i32x4*)&L[cbyte + sb0];
            b[fc][1] = *(const i32x4*)&L[cbyte + sb1];
        }
        // 4 phases: fr-pair {2q,2q+1} x 4 fc x 2 ks = 16 MFMA each
        #pragma unroll
        for (int q = 0; q < 4; ++q) {
            i32x4 a[2][2];
            #pragma unroll
            for (int i = 0; i < 2; ++i) {
                const int abyte = (((wr << 7) + ((2 * q + i) << 4) + rl) << 7);
                a[i][0] = *(const i32x4*)&L[abyte + sb0];
                a[i][1] = *(const i32x4*)&L[abyte + sb1];
            }
            __builtin_amdgcn_s_setprio(1);
            #pragma unroll
            for (int i = 0; i < 2; ++i)
                #pragma unroll
                for (int fc = 0; fc < 4; ++fc) {
                    acc[2 * q + i][fc] = __builtin_amdgcn_mfma_i32_16x16x64_i8(
                        a[i][0], b[fc][0], acc[2 * q + i][fc], 0, 0, 0);
                    acc[2 * q + i][fc] = __builtin_amdgcn_mfma_i32_16x16x64_i8(
                        a[i][1], b[fc][1], acc[2 * q + i][fc], 0, 0, 0);
                }
            __builtin_amdgcn_s_setprio(0);
        }

        if (kt < 31) {
            asm volatile("" ::: "memory");
            __builtin_amdgcn_s_barrier();          // all waves done reading cur
            asm volatile("" ::: "memory");
            if (kt < 30) {
                stage(kt + 2, kt & 1);             // overwrite cur (safe post-barrier)
                asm volatile("s_waitcnt vmcnt(8)" ::: "memory");  // stage(kt+1) landed
            } else {
                asm volatile("s_waitcnt vmcnt(0)" ::: "memory");  // drain stage(31)
            }
            __builtin_amdgcn_s_barrier();          // publish stage(kt+1)
            asm volatile("" ::: "memory");
        }
    }

    // epilogue: C/D map col=l&15, row=(l>>4)*4+q (R10-verified), fused loss
    float part = 0.0f;
    const int col = j0 + (wc << 6) + rl;
    #pragma unroll
    for (int fr = 0; fr < 8; ++fr)
        #pragma unroll
        for (int q = 0; q < 4; ++q) {
            size_t rbase = ((size_t)(b0 + (wr << 7) + (fr << 4) + (qh << 2) + q) << 12) + col;
            #pragma unroll
            for (int fc = 0; fc < 4; ++fc) {
                float yv = y[rbase + (fc << 4)];
                float hv = yhat[rbase + (fc << 4)];
                float e = yv - hv;
                float wgt = 0.1f * (float)acc[fr][fc][q] + (yv != 0.0f ? 1.0f : 0.0f);
                part = fmaf(e * e, wgt, part);
            }
        }

    for (int off = 32; off; off >>= 1) part += __shfl_down(part, off, 64);
    float* red = (float*)lds;
    __syncthreads();   // drains vmcnt/lgkm; safe to alias LDS
    if ((t & 63) == 0) red[t >> 6] = part;
    __syncthreads();
    if (t == 0) {
        float s = 0.0f;
        #pragma unroll
        for (int i = 0; i < 8; ++i) s += red[i];
        p3[(size_t)blockIdx.y * gridDim.x + blockIdx.x] = (double)s;
    }
}

// ================= popcount fallback path (R8, passing) =================

__global__ __launch_bounds__(256) void k1_pack_mask(
    const float* __restrict__ y, u64* __restrict__ mbT, u64* __restrict__ pcnt)
{
    __shared__ unsigned rc[4];
    const unsigned t = threadIdx.x;
    const unsigned lane = t & 63;
    const float4* y4 = (const float4*)y;
    u64 qi = (u64)blockIdx.x * 256 + t;
    const u64 stride = (u64)2048 * 256;
    unsigned lcnt = 0;
    #pragma unroll 4
    for (int it = 0; it < 16; ++it, qi += stride) {
        float4 v = y4[qi];
        u64 b0 = __ballot(v.x != 0.0f);
        u64 b1 = __ballot(v.y != 0.0f);
        u64 b2 = __ballot(v.z != 0.0f);
        u64 b3 = __ballot(v.w != 0.0f);
        lcnt += (v.x != 0.0f) + (v.y != 0.0f) + (v.z != 0.0f) + (v.w != 0.0f);
        if (lane < 4) {
            unsigned sh = lane << 4;
            u64 word = ((b0 >> sh) & 0xFFFFull)
                     | (((b1 >> sh) & 0xFFFFull) << 16)
                     | (((b2 >> sh) & 0xFFFFull) << 32)
                     | (((b3 >> sh) & 0xFFFFull) << 48);
            u64 gw = ((qi - lane) >> 4) + lane;
            mbT[((gw & 63) << 13) + (gw >> 6)] = word;
        }
    }
    for (int off = 32; off; off >>= 1) lcnt += __shfl_down(lcnt, off, 64);
    if ((t & 63) == 0) rc[t >> 6] = lcnt;
    __syncthreads();
    if (t == 0) pcnt[blockIdx.x] = (u64)rc[0] + rc[1] + rc[2] + rc[3];
}

__global__ __launch_bounds__(256) void k2_pack_w(
    const float* __restrict__ W, u64* __restrict__ wbT)
{
    __shared__ float tile[64][65];
    const int j0 = blockIdx.x * 64;
    const int w  = blockIdx.y;
    const int i0 = w * 64;
    const int t = threadIdx.x;
    #pragma unroll
    for (int k = 0; k < 16; ++k) {
        int lin = t + (k << 8);
        int r = lin >> 6, c = lin & 63;
        tile[r][c] = W[(size_t)(i0 + r) * NS + (j0 + c)];
    }
    __syncthreads();
    const int lane = t & 63;
    const int wvv = t >> 6;
    const int pr = ((lane & 15) << 2) + (lane >> 4);
    for (int jj = wvv; jj < 64; jj += 4) {
        u64 bal = __ballot(tile[pr][jj] != 0.0f);
        if (lane == 0) wbT[((size_t)w << 12) + (j0 + jj)] = bal;
    }
}

__global__ __launch_bounds__(256) void k3_main(
    const float* __restrict__ y, const float* __restrict__ yhat,
    const u64* __restrict__ mbT, const u64* __restrict__ wbT,
    double* __restrict__ p3)
{
    __shared__ alignas(16) u64 mT[16 * 128];
    __shared__ alignas(16) u64 wT[16 * 128];
    const int b0 = blockIdx.x << 7;
    const int j0 = blockIdx.y << 7;
    const int t  = threadIdx.x;
    const int r0 = (t >> 4) << 3;
    const int cj = t & 15;
    const unsigned sx = ((unsigned)cj >> 2) << 4;

    unsigned cnt[8][8];
    #pragma unroll
    for (int a = 0; a < 8; ++a)
        #pragma unroll
        for (int b = 0; b < 8; ++b) cnt[a][b] = 0;

    char* mB = (char*)mT;
    char* wB = (char*)wT;

    #pragma unroll 1
    for (int s = 0; s < 4; ++s) {
        u64x2 gm[4], gq[4];
        #pragma unroll
        for (int k = 0; k < 4; ++k) {
            int lin = t + (k << 8);
            int wl = (s << 4) + (lin >> 6), c2 = lin & 63;
            gm[k] = *(const u64x2*)&mbT[((size_t)wl << 13) + b0 + 2 * c2];
            gq[k] = *(const u64x2*)&wbT[((size_t)wl << 12) + j0 + 2 * c2];
        }
        __syncthreads();
        #pragma unroll
        for (int k = 0; k < 4; ++k) {
            int lin = t + (k << 8);
            int wl = lin >> 6, c2 = lin & 63;
            int p = c2 ^ ((c2 >> 4) & 3);
            *(u64x2*)(mB + (wl << 10) + (c2 << 4)) = gm[k];
            *(u64x2*)(wB + (wl << 10) + (p << 4)) = gq[k];
        }
        __syncthreads();

        unsigned mo = (unsigned)(r0 << 3);
        unsigned qs = (unsigned)(cj << 6) + sx;
        #pragma unroll 2
        for (int w = 0; w < 16; ++w) {
            unsigned ml[16], ql[16];
            #pragma unroll
            for (int k = 0; k < 4; ++k) {
                uint4 a = *(const uint4*)(mB + mo + (k << 4));
                ml[4 * k + 0] = a.x; ml[4 * k + 1] = a.y;
                ml[4 * k + 2] = a.z; ml[4 * k + 3] = a.w;
                uint4 b = *(const uint4*)(wB + (qs ^ (unsigned)(k << 4)));
                ql[4 * k + 0] = b.x; ql[4 * k + 1] = b.y;
                ql[4 * k + 2] = b.z; ql[4 * k + 3] = b.w;
            }
            #pragma unroll
            for (int aa = 0; aa < 8; ++aa)
                #pragma unroll
                for (int bb = 0; bb < 8; ++bb) {
                    unsigned x0 = ml[2 * aa] & ql[2 * bb];
                    unsigned x1 = ml[2 * aa + 1] & ql[2 * bb + 1];
                    asm("v_bcnt_u32_b32 %0, %1, %0" : "+v"(cnt[aa][bb]) : "v"(x0));
                    asm("v_bcnt_u32_b32 %0, %1, %0" : "+v"(cnt[aa][bb]) : "v"(x1));
                }
            mo += 1024; qs += 1024;
        }
    }

    float part = 0.0f;
    const int c0 = cj << 3;
    #pragma unroll
    for (int aa = 0; aa < 8; ++aa) {
        size_t off = ((size_t)(b0 + r0 + aa) << 12) + (size_t)(j0 + c0);
        float ys[8], hs[8];
        *(float4*)&ys[0] = *(const float4*)(y + off);
        *(float4*)&ys[4] = *(const float4*)(y + off + 4);
        *(float4*)&hs[0] = *(const float4*)(yhat + off);
        *(float4*)&hs[4] = *(const float4*)(yhat + off + 4);
        #pragma unroll
        for (int bb = 0; bb < 8; ++bb) {
            float e = ys[bb] - hs[bb];
            float wgt = 0.1f * (float)cnt[aa][bb] + (ys[bb] != 0.0f ? 1.0f : 0.0f);
            part = fmaf(e * e, wgt, part);
        }
    }

    for (int off = 32; off; off >>= 1) part += __shfl_down(part, off, 64);
    float* red = (float*)mT;
    __syncthreads();
    if ((t & 63) == 0) red[t >> 6] = part;
    __syncthreads();
    if (t == 0)
        p3[(size_t)blockIdx.y * gridDim.x + blockIdx.x] =
            (double)red[0] + (double)red[1] + (double)red[2] + (double)red[3];
}

// ---------------- K4: final reduce + sqrt (np3 = valid p3 entries) ----------------
__global__ __launch_bounds__(256) void k4_final(
    const u64* __restrict__ pcnt, const double* __restrict__ p3, float* __restrict__ out,
    int np3)
{
    __shared__ double rs[4];
    __shared__ u64 rcc[4];
    double s3 = 0.0;
    u64 c = 0;
    for (int i = threadIdx.x; i < 2048; i += 256) c += pcnt[i];
    for (int i = threadIdx.x; i < np3; i += 256) s3 += p3[i];
    for (int off = 32; off; off >>= 1) {
        s3 += __shfl_down(s3, off, 64);
        c  += __shfl_down(c, off, 64);
    }
    int wv = threadIdx.x >> 6;
    if ((threadIdx.x & 63) == 0) { rs[wv] = s3; rcc[wv] = c; }
    __syncthreads();
    if (threadIdx.x == 0) {
        double S3 = rs[0] + rs[1] + rs[2] + rs[3];
        double C  = (double)(rcc[0] + rcc[1] + rcc[2] + rcc[3]);
        out[0] = (float)sqrt(S3 / C + 1e-6);
    }
}

extern "C" void kernel_launch(void* const* d_in, const int* in_sizes, int n_in,
                              void* d_out, int out_size, void* d_ws, size_t ws_size,
                              hipStream_t stream) {
    const float* yhat = (const float*)d_in[0];
    const float* y    = (const float*)d_in[1];
    const float* W    = (const float*)d_in[2];
    char* ws = (char*)d_ws;
    u64*    pcnt = (u64*)(ws + OFF_CNT);
    double* p3   = (double*)(ws + OFF_P3);

    if (ws_size >= WS_NEED) {
        u32* m8 = (u32*)(ws + OFF_M8);
        u32* bt = (u32*)(ws + OFF_BT);
        k12_prep<<<dim3(2048 + 4096), dim3(256), 0, stream>>>(y, W, m8, bt, pcnt);
        k3g_mfma<<<dim3(32, 16), dim3(512), 0, stream>>>(
            y, yhat, (const u8*)m8, (const u8*)bt, p3);
        k4_final<<<dim3(1), dim3(256), 0, stream>>>(pcnt, p3, (float*)d_out, 512);
    } else {
        u64* mbT = (u64*)(ws + OFF_MB);
        u64* wbT = (u64*)(ws + OFF_WB);
        k1_pack_mask<<<dim3(2048), dim3(256), 0, stream>>>(y, mbT, pcnt);
        k2_pack_w<<<dim3(64, 64), dim3(256), 0, stream>>>(W, wbT);
        k3_main<<<dim3(64, 32), dim3(256), 0, stream>>>(y, yhat, mbT, wbT, p3);
        k4_final<<<dim3(1), dim3(256), 0, stream>>>(pcnt, p3, (float*)d_out, 2048);
    }
}

// Round 20
// 190.914 us; speedup vs baseline: 1.8079x; 1.0485x over previous
//
#include <hip/hip_runtime.h>
#include <math.h>

typedef unsigned long long u64;
typedef unsigned int u32;
typedef unsigned char u8;
typedef __attribute__((ext_vector_type(2))) unsigned long long u64x2;
typedef __attribute__((ext_vector_type(4))) int i32x4;

#define NB 8192
#define NS 4096

// ---- ws layout ----
static const size_t OFF_CNT = 0;                            // pcnt[2048] u64
static const size_t OFF_P3  = 16384;                        // p3[<=2048] double
static const size_t OFF_M8  = 32768;                        // mask8 [8192][4096] i8
static const size_t OFF_BT  = OFF_M8 + (size_t)NB * NS;     // Bt [4096][4096] i8
static const size_t WS_NEED = OFF_BT + (size_t)NS * NS;     // ~48 MB (proven available)
static const size_t OFF_MB  = 32768;                        // popcount fallback layout
static const size_t OFF_WB  = OFF_MB + (size_t)64 * NB * 8;

__device__ __forceinline__ void gload_lds16(const void* g, void* l) {
    __builtin_amdgcn_global_load_lds(
        (const __attribute__((address_space(1))) unsigned int*)g,
        (__attribute__((address_space(3))) unsigned int*)l, 16, 0, 0);
}

// ================= i8-MFMA path =================

// K12: fused prep (R17-verified). g<2048: mask8+pcnt over y. g>=2048: Bt of W.
__global__ __launch_bounds__(256) void k12_prep(
    const float* __restrict__ y, const float* __restrict__ W,
    u32* __restrict__ m8, u32* __restrict__ bt, u64* __restrict__ pcnt)
{
    const int g = blockIdx.x;
    const int t = threadIdx.x;
    if (g < 2048) {
        __shared__ unsigned rc[4];
        const float4* y4 = (const float4*)y;
        size_t base = (size_t)g * 4096 + t;
        unsigned lcnt = 0;
        #pragma unroll 4
        for (int k = 0; k < 16; ++k) {
            float4 v = y4[base + (size_t)k * 256];
            unsigned b0 = v.x != 0.0f, b1 = v.y != 0.0f, b2 = v.z != 0.0f, b3 = v.w != 0.0f;
            lcnt += b0 + b1 + b2 + b3;
            m8[base + (size_t)k * 256] = b0 | (b1 << 8) | (b2 << 16) | (b3 << 24);
        }
        for (int off = 32; off; off >>= 1) lcnt += __shfl_down(lcnt, off, 64);
        if ((t & 63) == 0) rc[t >> 6] = lcnt;
        __syncthreads();
        if (t == 0) pcnt[g] = (u64)rc[0] + rc[1] + rc[2] + rc[3];
    } else {
        __shared__ float tile[64][65];
        const int gg = g - 2048;
        const int j0 = (gg & 63) * 64, i0 = (gg >> 6) * 64;
        #pragma unroll
        for (int k = 0; k < 16; ++k) {
            int lin = t + (k << 8);
            int r = lin >> 6, c = lin & 63;
            tile[r][c] = W[(size_t)(i0 + r) * NS + (j0 + c)];
        }
        __syncthreads();
        const int jj = t >> 2, ck = t & 3;
        u32 wd[4];
        #pragma unroll
        for (int gq = 0; gq < 4; ++gq) {
            u32 u = 0;
            #pragma unroll
            for (int bb = 0; bb < 4; ++bb)
                u |= (tile[ck * 16 + gq * 4 + bb][jj] != 0.0f ? 1u : 0u) << (8 * bb);
            wd[gq] = u;
        }
        uint4 out = make_uint4(wd[0], wd[1], wd[2], wd[3]);
        *(uint4*)&bt[(((size_t)(j0 + jj) << 12) + (size_t)(i0 + ck * 16)) >> 2] = out;
    }
}

// K3g v2: 256x256 i8 GEMM, half-tile-granular 8-phase-per-2-K-tiles pipeline.
// LDS: 4 regions/operand ([dbuf][half] 16KB each, 128KB total) so staging
// overlaps reading. Per K-tile: q0 {stage A.h0(m+1) | read B(8)+A(4) | 16 MFMA
// | barrier}, q1 {stage A.h1(m+1) | A | MFMA}, q2/q3 {stage B.h(m+2) | A |
// MFMA}. Tile-start: vmcnt(N)+barrier, N = 8 (m=0) / 0 (m=31) / 4. Swizzle
// slot^=(row&7) via pre-swizzled source + read XOR (R19-verified, 0 conflict).
__global__ __launch_bounds__(512, 2) void k3g_mfma(
    const float* __restrict__ y, const float* __restrict__ yhat,
    const u8* __restrict__ m8, const u8* __restrict__ bt,
    double* __restrict__ p3)
{
    __shared__ alignas(16) u8 lds[131072];   // A: [d][h] 4x16KB @0; B: 4x16KB @65536
    const int b0 = blockIdx.x << 8;    // 32 row tiles (256 rows)
    const int j0 = blockIdx.y << 8;    // 16 col tiles (256 cols)
    const int t = threadIdx.x, l = t & 63, wv = t >> 6;   // 8 waves
    const int wr = wv >> 2, wc = wv & 3;                  // 2M x 4N

    const int srow = t >> 3;                    // 0..63
    const int schunk = (t & 7) ^ (srow & 7);    // pre-swizzled source chunk

    // half-tile stagers: 2 gloads each; dest linear (base + i*8192), src rows
    // h*128 + i*64 + srow, k-bytes kt*128 + schunk*16
    auto stageA = [&](int kt, int h) {
        const u8* src = m8 + ((size_t)(b0 + (h << 7) + srow) << 12)
                        + (size_t)((kt << 7) + (schunk << 4));
        u8* d = &lds[((((kt & 1) << 1) + h) << 14) + (wv << 10)];
        gload_lds16(src, d);
        gload_lds16(src + ((size_t)64 << 12), d + 8192);
    };
    auto stageB = [&](int kt, int h) {
        const u8* src = bt + ((size_t)(j0 + (h << 7) + srow) << 12)
                        + (size_t)((kt << 7) + (schunk << 4));
        u8* d = &lds[65536 + ((((kt & 1) << 1) + h) << 14) + (wv << 10)];
        gload_lds16(src, d);
        gload_lds16(src + ((size_t)64 << 12), d + 8192);
    };

    // frag read swizzle: slot = (ks*4 + qh) ^ (row&7), row&7 == l&7
    const int rl = l & 15, qh = l >> 4, rx = l & 7;
    const int sb0 = ((qh ^ rx) << 4);
    const int sb1 = (((4 + qh) ^ rx) << 4);
    const int bro = (wc & 1) << 6;   // B within-half base row

    i32x4 acc[8][4];
    #pragma unroll
    for (int i = 0; i < 8; ++i)
        #pragma unroll
        for (int j = 0; j < 4; ++j) acc[i][j] = (i32x4){0, 0, 0, 0};

    // prologue: tiles 0 and 1 (16 loads/thread)
    stageA(0, 0); stageA(0, 1); stageB(0, 0); stageB(0, 1);
    stageA(1, 0); stageA(1, 1); stageB(1, 0); stageB(1, 1);

    #pragma unroll 1
    for (int m = 0; m < 32; ++m) {
        const int d = m & 1;
        if (m == 0)       { asm volatile("s_waitcnt vmcnt(8)" ::: "memory"); }
        else if (m == 31) { asm volatile("s_waitcnt vmcnt(0)" ::: "memory"); }
        else              { asm volatile("s_waitcnt vmcnt(4)" ::: "memory"); }
        __builtin_amdgcn_s_barrier();          // A(m), B(m) published
        asm volatile("" ::: "memory");

        const u8* LA = &lds[(((d << 1) + wr) << 14)];
        const u8* LB = &lds[65536 + (((d << 1) + (wc >> 1)) << 14)];

        i32x4 b[4][2];
        #pragma unroll
        for (int q = 0; q < 4; ++q) {
            // per-phase staging (slot table; guards for prologue/tail)
            if (q == 0) { if (m >= 1 && m <= 30) stageA(m + 1, 0); }
            else if (q == 1) { if (m >= 1 && m <= 30) stageA(m + 1, 1); }
            else if (q == 2) { if (m <= 29) stageB(m + 2, 0); }
            else             { if (m <= 29) stageB(m + 2, 1); }

            if (q == 0) {   // B for the whole tile, kept in regs
                #pragma unroll
                for (int fc = 0; fc < 4; ++fc) {
                    const int lr = bro + (fc << 4) + rl;
                    b[fc][0] = *(const i32x4*)&LB[(lr << 7) + sb0];
                    b[fc][1] = *(const i32x4*)&LB[(lr << 7) + sb1];
                }
            }
            i32x4 a[2][2];
            #pragma unroll
            for (int i = 0; i < 2; ++i) {
                const int lr = (((q << 1) + i) << 4) + rl;
                a[i][0] = *(const i32x4*)&LA[(lr << 7) + sb0];
                a[i][1] = *(const i32x4*)&LA[(lr << 7) + sb1];
            }
            __builtin_amdgcn_s_setprio(1);
            #pragma unroll
            for (int i = 0; i < 2; ++i)
                #pragma unroll
                for (int fc = 0; fc < 4; ++fc) {
                    acc[2 * q + i][fc] = __builtin_amdgcn_mfma_i32_16x16x64_i8(
                        a[i][0], b[fc][0], acc[2 * q + i][fc], 0, 0, 0);
                    acc[2 * q + i][fc] = __builtin_amdgcn_mfma_i32_16x16x64_i8(
                        a[i][1], b[fc][1], acc[2 * q + i][fc], 0, 0, 0);
                }
            __builtin_amdgcn_s_setprio(0);

            if (q == 0) {   // release B[d] (all waves' B reads done pre-MFMA)
                asm volatile("" ::: "memory");
                __builtin_amdgcn_s_barrier();
                asm volatile("" ::: "memory");
            }
        }
        // next tile's vmcnt+barrier doubles as the A[d]-release barrier
    }

    // epilogue: C/D map col=l&15, row=(l>>4)*4+q (R10-verified), fused loss
    float part = 0.0f;
    const int col = j0 + (wc << 6) + rl;
    #pragma unroll
    for (int fr = 0; fr < 8; ++fr)
        #pragma unroll
        for (int q = 0; q < 4; ++q) {
            size_t rbase = ((size_t)(b0 + (wr << 7) + (fr << 4) + (qh << 2) + q) << 12) + col;
            #pragma unroll
            for (int fc = 0; fc < 4; ++fc) {
                float yv = y[rbase + (fc << 4)];
                float hv = yhat[rbase + (fc << 4)];
                float e = yv - hv;
                float wgt = 0.1f * (float)acc[fr][fc][q] + (yv != 0.0f ? 1.0f : 0.0f);
                part = fmaf(e * e, wgt, part);
            }
        }

    for (int off = 32; off; off >>= 1) part += __shfl_down(part, off, 64);
    float* red = (float*)lds;
    __syncthreads();   // drains all counters; safe to alias LDS
    if ((t & 63) == 0) red[t >> 6] = part;
    __syncthreads();
    if (t == 0) {
        float s = 0.0f;
        #pragma unroll
        for (int i = 0; i < 8; ++i) s += red[i];
        p3[(size_t)blockIdx.y * gridDim.x + blockIdx.x] = (double)s;
    }
}

// ================= popcount fallback path (R8, passing) =================

__global__ __launch_bounds__(256) void k1_pack_mask(
    const float* __restrict__ y, u64* __restrict__ mbT, u64* __restrict__ pcnt)
{
    __shared__ unsigned rc[4];
    const unsigned t = threadIdx.x;
    const unsigned lane = t & 63;
    const float4* y4 = (const float4*)y;
    u64 qi = (u64)blockIdx.x * 256 + t;
    const u64 stride = (u64)2048 * 256;
    unsigned lcnt = 0;
    #pragma unroll 4
    for (int it = 0; it < 16; ++it, qi += stride) {
        float4 v = y4[qi];
        u64 b0 = __ballot(v.x != 0.0f);
        u64 b1 = __ballot(v.y != 0.0f);
        u64 b2 = __ballot(v.z != 0.0f);
        u64 b3 = __ballot(v.w != 0.0f);
        lcnt += (v.x != 0.0f) + (v.y != 0.0f) + (v.z != 0.0f) + (v.w != 0.0f);
        if (lane < 4) {
            unsigned sh = lane << 4;
            u64 word = ((b0 >> sh) & 0xFFFFull)
                     | (((b1 >> sh) & 0xFFFFull) << 16)
                     | (((b2 >> sh) & 0xFFFFull) << 32)
                     | (((b3 >> sh) & 0xFFFFull) << 48);
            u64 gw = ((qi - lane) >> 4) + lane;
            mbT[((gw & 63) << 13) + (gw >> 6)] = word;
        }
    }
    for (int off = 32; off; off >>= 1) lcnt += __shfl_down(lcnt, off, 64);
    if ((t & 63) == 0) rc[t >> 6] = lcnt;
    __syncthreads();
    if (t == 0) pcnt[blockIdx.x] = (u64)rc[0] + rc[1] + rc[2] + rc[3];
}

__global__ __launch_bounds__(256) void k2_pack_w(
    const float* __restrict__ W, u64* __restrict__ wbT)
{
    __shared__ float tile[64][65];
    const int j0 = blockIdx.x * 64;
    const int w  = blockIdx.y;
    const int i0 = w * 64;
    const int t = threadIdx.x;
    #pragma unroll
    for (int k = 0; k < 16; ++k) {
        int lin = t + (k << 8);
        int r = lin >> 6, c = lin & 63;
        tile[r][c] = W[(size_t)(i0 + r) * NS + (j0 + c)];
    }
    __syncthreads();
    const int lane = t & 63;
    const int wvv = t >> 6;
    const int pr = ((lane & 15) << 2) + (lane >> 4);
    for (int jj = wvv; jj < 64; jj += 4) {
        u64 bal = __ballot(tile[pr][jj] != 0.0f);
        if (lane == 0) wbT[((size_t)w << 12) + (j0 + jj)] = bal;
    }
}

__global__ __launch_bounds__(256) void k3_main(
    const float* __restrict__ y, const float* __restrict__ yhat,
    const u64* __restrict__ mbT, const u64* __restrict__ wbT,
    double* __restrict__ p3)
{
    __shared__ alignas(16) u64 mT[16 * 128];
    __shared__ alignas(16) u64 wT[16 * 128];
    const int b0 = blockIdx.x << 7;
    const int j0 = blockIdx.y << 7;
    const int t  = threadIdx.x;
    const int r0 = (t >> 4) << 3;
    const int cj = t & 15;
    const unsigned sx = ((unsigned)cj >> 2) << 4;

    unsigned cnt[8][8];
    #pragma unroll
    for (int a = 0; a < 8; ++a)
        #pragma unroll
        for (int b = 0; b < 8; ++b) cnt[a][b] = 0;

    char* mB = (char*)mT;
    char* wB = (char*)wT;

    #pragma unroll 1
    for (int s = 0; s < 4; ++s) {
        u64x2 gm[4], gq[4];
        #pragma unroll
        for (int k = 0; k < 4; ++k) {
            int lin = t + (k << 8);
            int wl = (s << 4) + (lin >> 6), c2 = lin & 63;
            gm[k] = *(const u64x2*)&mbT[((size_t)wl << 13) + b0 + 2 * c2];
            gq[k] = *(const u64x2*)&wbT[((size_t)wl << 12) + j0 + 2 * c2];
        }
        __syncthreads();
        #pragma unroll
        for (int k = 0; k < 4; ++k) {
            int lin = t + (k << 8);
            int wl = lin >> 6, c2 = lin & 63;
            int p = c2 ^ ((c2 >> 4) & 3);
            *(u64x2*)(mB + (wl << 10) + (c2 << 4)) = gm[k];
            *(u64x2*)(wB + (wl << 10) + (p << 4)) = gq[k];
        }
        __syncthreads();

        unsigned mo = (unsigned)(r0 << 3);
        unsigned qs = (unsigned)(cj << 6) + sx;
        #pragma unroll 2
        for (int w = 0; w < 16; ++w) {
            unsigned ml[16], ql[16];
            #pragma unroll
            for (int k = 0; k < 4; ++k) {
                uint4 a = *(const uint4*)(mB + mo + (k << 4));
                ml[4 * k + 0] = a.x; ml[4 * k + 1] = a.y;
                ml[4 * k + 2] = a.z; ml[4 * k + 3] = a.w;
                uint4 b = *(const uint4*)(wB + (qs ^ (unsigned)(k << 4)));
                ql[4 * k + 0] = b.x; ql[4 * k + 1] = b.y;
                ql[4 * k + 2] = b.z; ql[4 * k + 3] = b.w;
            }
            #pragma unroll
            for (int aa = 0; aa < 8; ++aa)
                #pragma unroll
                for (int bb = 0; bb < 8; ++bb) {
                    unsigned x0 = ml[2 * aa] & ql[2 * bb];
                    unsigned x1 = ml[2 * aa + 1] & ql[2 * bb + 1];
                    asm("v_bcnt_u32_b32 %0, %1, %0" : "+v"(cnt[aa][bb]) : "v"(x0));
                    asm("v_bcnt_u32_b32 %0, %1, %0" : "+v"(cnt[aa][bb]) : "v"(x1));
                }
            mo += 1024; qs += 1024;
        }
    }

    float part = 0.0f;
    const int c0 = cj << 3;
    #pragma unroll
    for (int aa = 0; aa < 8; ++aa) {
        size_t off = ((size_t)(b0 + r0 + aa) << 12) + (size_t)(j0 + c0);
        float ys[8], hs[8];
        *(float4*)&ys[0] = *(const float4*)(y + off);
        *(float4*)&ys[4] = *(const float4*)(y + off + 4);
        *(float4*)&hs[0] = *(const float4*)(yhat + off);
        *(float4*)&hs[4] = *(const float4*)(yhat + off + 4);
        #pragma unroll
        for (int bb = 0; bb < 8; ++bb) {
            float e = ys[bb] - hs[bb];
            float wgt = 0.1f * (float)cnt[aa][bb] + (ys[bb] != 0.0f ? 1.0f : 0.0f);
            part = fmaf(e * e, wgt, part);
        }
    }

    for (int off = 32; off; off >>= 1) part += __shfl_down(part, off, 64);
    float* red = (float*)mT;
    __syncthreads();
    if ((t & 63) == 0) red[t >> 6] = part;
    __syncthreads();
    if (t == 0)
        p3[(size_t)blockIdx.y * gridDim.x + blockIdx.x] =
            (double)red[0] + (double)red[1] + (double)red[2] + (double)red[3];
}

// ---------------- K4: final reduce + sqrt (np3 = valid p3 entries) ----------------
__global__ __launch_bounds__(256) void k4_final(
    const u64* __restrict__ pcnt, const double* __restrict__ p3, float* __restrict__ out,
    int np3)
{
    __shared__ double rs[4];
    __shared__ u64 rcc[4];
    double s3 = 0.0;
    u64 c = 0;
    for (int i = threadIdx.x; i < 2048; i += 256) c += pcnt[i];
    for (int i = threadIdx.x; i < np3; i += 256) s3 += p3[i];
    for (int off = 32; off; off >>= 1) {
        s3 += __shfl_down(s3, off, 64);
        c  += __shfl_down(c, off, 64);
    }
    int wv = threadIdx.x >> 6;
    if ((threadIdx.x & 63) == 0) { rs[wv] = s3; rcc[wv] = c; }
    __syncthreads();
    if (threadIdx.x == 0) {
        double S3 = rs[0] + rs[1] + rs[2] + rs[3];
        double C  = (double)(rcc[0] + rcc[1] + rcc[2] + rcc[3]);
        out[0] = (float)sqrt(S3 / C + 1e-6);
    }
}

extern "C" void kernel_launch(void* const* d_in, const int* in_sizes, int n_in,
                              void* d_out, int out_size, void* d_ws, size_t ws_size,
                              hipStream_t stream) {
    const float* yhat = (const float*)d_in[0];
    const float* y    = (const float*)d_in[1];
    const float* W    = (const float*)d_in[2];
    char* ws = (char*)d_ws;
    u64*    pcnt = (u64*)(ws + OFF_CNT);
    double* p3   = (double*)(ws + OFF_P3);

    if (ws_size >= WS_NEED) {
        u32* m8 = (u32*)(ws + OFF_M8);
        u32* bt = (u32*)(ws + OFF_BT);
        k12_prep<<<dim3(2048 + 4096), dim3(256), 0, stream>>>(y, W, m8, bt, pcnt);
        k3g_mfma<<<dim3(32, 16), dim3(512), 0, stream>>>(
            y, yhat, (const u8*)m8, (const u8*)bt, p3);
        k4_final<<<dim3(1), dim3(256), 0, stream>>>(pcnt, p3, (float*)d_out, 512);
    } else {
        u64* mbT = (u64*)(ws + OFF_MB);
        u64* wbT = (u64*)(ws + OFF_WB);
        k1_pack_mask<<<dim3(2048), dim3(256), 0, stream>>>(y, mbT, pcnt);
        k2_pack_w<<<dim3(64, 64), dim3(256), 0, stream>>>(W, wbT);
        k3_main<<<dim3(64, 32), dim3(256), 0, stream>>>(y, yhat, mbT, wbT, p3);
        k4_final<<<dim3(1), dim3(256), 0, stream>>>(pcnt, p3, (float*)d_out, 2048);
    }
}

// Round 21
// 190.057 us; speedup vs baseline: 1.8161x; 1.0045x over previous
//
#include <hip/hip_runtime.h>
#include <math.h>

typedef unsigned long long u64;
typedef unsigned int u32;
typedef unsigned char u8;
typedef __attribute__((ext_vector_type(2))) unsigned long long u64x2;
typedef __attribute__((ext_vector_type(4))) int i32x4;

#define NB 8192
#define NS 4096

// ---- ws layout ----
static const size_t OFF_CNT = 0;                            // pcnt[2048] u64
static const size_t OFF_P3  = 16384;                        // p3[<=2048] double
static const size_t OFF_M8  = 32768;                        // mask8 [8192][4096] i8
static const size_t OFF_BT  = OFF_M8 + (size_t)NB * NS;     // Bt [4096][4096] i8
static const size_t WS_NEED = OFF_BT + (size_t)NS * NS;     // ~48 MB (proven available)
static const size_t OFF_MB  = 32768;                        // popcount fallback layout
static const size_t OFF_WB  = OFF_MB + (size_t)64 * NB * 8;

__device__ __forceinline__ void gload_lds16(const void* g, void* l) {
    __builtin_amdgcn_global_load_lds(
        (const __attribute__((address_space(1))) unsigned int*)g,
        (__attribute__((address_space(3))) unsigned int*)l, 16, 0, 0);
}

// ================= i8-MFMA path =================

// K12: fused prep (R17-verified). g<2048: mask8+pcnt over y. g>=2048: Bt of W.
__global__ __launch_bounds__(256) void k12_prep(
    const float* __restrict__ y, const float* __restrict__ W,
    u32* __restrict__ m8, u32* __restrict__ bt, u64* __restrict__ pcnt)
{
    const int g = blockIdx.x;
    const int t = threadIdx.x;
    if (g < 2048) {
        __shared__ unsigned rc[4];
        const float4* y4 = (const float4*)y;
        size_t base = (size_t)g * 4096 + t;
        unsigned lcnt = 0;
        #pragma unroll 4
        for (int k = 0; k < 16; ++k) {
            float4 v = y4[base + (size_t)k * 256];
            unsigned b0 = v.x != 0.0f, b1 = v.y != 0.0f, b2 = v.z != 0.0f, b3 = v.w != 0.0f;
            lcnt += b0 + b1 + b2 + b3;
            m8[base + (size_t)k * 256] = b0 | (b1 << 8) | (b2 << 16) | (b3 << 24);
        }
        for (int off = 32; off; off >>= 1) lcnt += __shfl_down(lcnt, off, 64);
        if ((t & 63) == 0) rc[t >> 6] = lcnt;
        __syncthreads();
        if (t == 0) pcnt[g] = (u64)rc[0] + rc[1] + rc[2] + rc[3];
    } else {
        __shared__ float tile[64][65];
        const int gg = g - 2048;
        const int j0 = (gg & 63) * 64, i0 = (gg >> 6) * 64;
        #pragma unroll
        for (int k = 0; k < 16; ++k) {
            int lin = t + (k << 8);
            int r = lin >> 6, c = lin & 63;
            tile[r][c] = W[(size_t)(i0 + r) * NS + (j0 + c)];
        }
        __syncthreads();
        const int jj = t >> 2, ck = t & 3;
        u32 wd[4];
        #pragma unroll
        for (int gq = 0; gq < 4; ++gq) {
            u32 u = 0;
            #pragma unroll
            for (int bb = 0; bb < 4; ++bb)
                u |= (tile[ck * 16 + gq * 4 + bb][jj] != 0.0f ? 1u : 0u) << (8 * bb);
            wd[gq] = u;
        }
        uint4 out = make_uint4(wd[0], wd[1], wd[2], wd[3]);
        *(uint4*)&bt[(((size_t)(j0 + jj) << 12) + (size_t)(i0 + ck * 16)) >> 2] = out;
    }
}

// K3g v3: R20 pipeline + XCD-aware chunked block swizzle (T1).
// Default x-fastest dispatch puts 8 consecutive blocks on 8 XCDs, thrashing
// each XCD L2 with all 16 bt column panels. swz = (lin&7)*64 + lin>>3 is
// bijective (512 blocks % 8 == 0) and gives each XCD a contiguous run of 64
// blocks = 2 bt panels (2MB <= 4MB L2) -> B staging becomes L2-resident.
__global__ __launch_bounds__(512, 2) void k3g_mfma(
    const float* __restrict__ y, const float* __restrict__ yhat,
    const u8* __restrict__ m8, const u8* __restrict__ bt,
    double* __restrict__ p3)
{
    __shared__ alignas(16) u8 lds[131072];   // A: [d][h] 4x16KB @0; B: 4x16KB @65536
    const int lin = blockIdx.x + (blockIdx.y << 5);      // 0..511, x fastest
    const int swz = ((lin & 7) << 6) + (lin >> 3);       // chunked per-XCD (bijective)
    const int bx = swz & 31, by = swz >> 5;
    const int b0 = bx << 8;    // 32 row tiles (256 rows)
    const int j0 = by << 8;    // 16 col tiles (256 cols)
    const int t = threadIdx.x, l = t & 63, wv = t >> 6;   // 8 waves
    const int wr = wv >> 2, wc = wv & 3;                  // 2M x 4N

    const int srow = t >> 3;                    // 0..63
    const int schunk = (t & 7) ^ (srow & 7);    // pre-swizzled source chunk

    auto stageA = [&](int kt, int h) {
        const u8* src = m8 + ((size_t)(b0 + (h << 7) + srow) << 12)
                        + (size_t)((kt << 7) + (schunk << 4));
        u8* d = &lds[((((kt & 1) << 1) + h) << 14) + (wv << 10)];
        gload_lds16(src, d);
        gload_lds16(src + ((size_t)64 << 12), d + 8192);
    };
    auto stageB = [&](int kt, int h) {
        const u8* src = bt + ((size_t)(j0 + (h << 7) + srow) << 12)
                        + (size_t)((kt << 7) + (schunk << 4));
        u8* d = &lds[65536 + ((((kt & 1) << 1) + h) << 14) + (wv << 10)];
        gload_lds16(src, d);
        gload_lds16(src + ((size_t)64 << 12), d + 8192);
    };

    // frag read swizzle: slot = (ks*4 + qh) ^ (row&7), row&7 == l&7
    const int rl = l & 15, qh = l >> 4, rx = l & 7;
    const int sb0 = ((qh ^ rx) << 4);
    const int sb1 = (((4 + qh) ^ rx) << 4);
    const int bro = (wc & 1) << 6;   // B within-half base row

    i32x4 acc[8][4];
    #pragma unroll
    for (int i = 0; i < 8; ++i)
        #pragma unroll
        for (int j = 0; j < 4; ++j) acc[i][j] = (i32x4){0, 0, 0, 0};

    // prologue: tiles 0 and 1 (16 loads/thread)
    stageA(0, 0); stageA(0, 1); stageB(0, 0); stageB(0, 1);
    stageA(1, 0); stageA(1, 1); stageB(1, 0); stageB(1, 1);

    #pragma unroll 1
    for (int m = 0; m < 32; ++m) {
        const int d = m & 1;
        if (m == 0)       { asm volatile("s_waitcnt vmcnt(8)" ::: "memory"); }
        else if (m == 31) { asm volatile("s_waitcnt vmcnt(0)" ::: "memory"); }
        else              { asm volatile("s_waitcnt vmcnt(4)" ::: "memory"); }
        __builtin_amdgcn_s_barrier();          // A(m), B(m) published
        asm volatile("" ::: "memory");

        const u8* LA = &lds[(((d << 1) + wr) << 14)];
        const u8* LB = &lds[65536 + (((d << 1) + (wc >> 1)) << 14)];

        i32x4 b[4][2];
        #pragma unroll
        for (int q = 0; q < 4; ++q) {
            if (q == 0) { if (m >= 1 && m <= 30) stageA(m + 1, 0); }
            else if (q == 1) { if (m >= 1 && m <= 30) stageA(m + 1, 1); }
            else if (q == 2) { if (m <= 29) stageB(m + 2, 0); }
            else             { if (m <= 29) stageB(m + 2, 1); }

            if (q == 0) {   // B for the whole tile, kept in regs
                #pragma unroll
                for (int fc = 0; fc < 4; ++fc) {
                    const int lr = bro + (fc << 4) + rl;
                    b[fc][0] = *(const i32x4*)&LB[(lr << 7) + sb0];
                    b[fc][1] = *(const i32x4*)&LB[(lr << 7) + sb1];
                }
            }
            i32x4 a[2][2];
            #pragma unroll
            for (int i = 0; i < 2; ++i) {
                const int lr = (((q << 1) + i) << 4) + rl;
                a[i][0] = *(const i32x4*)&LA[(lr << 7) + sb0];
                a[i][1] = *(const i32x4*)&LA[(lr << 7) + sb1];
            }
            __builtin_amdgcn_s_setprio(1);
            #pragma unroll
            for (int i = 0; i < 2; ++i)
                #pragma unroll
                for (int fc = 0; fc < 4; ++fc) {
                    acc[2 * q + i][fc] = __builtin_amdgcn_mfma_i32_16x16x64_i8(
                        a[i][0], b[fc][0], acc[2 * q + i][fc], 0, 0, 0);
                    acc[2 * q + i][fc] = __builtin_amdgcn_mfma_i32_16x16x64_i8(
                        a[i][1], b[fc][1], acc[2 * q + i][fc], 0, 0, 0);
                }
            __builtin_amdgcn_s_setprio(0);

            if (q == 0) {   // release B[d]
                asm volatile("" ::: "memory");
                __builtin_amdgcn_s_barrier();
                asm volatile("" ::: "memory");
            }
        }
    }

    // epilogue: C/D map col=l&15, row=(l>>4)*4+q (R10-verified), fused loss
    float part = 0.0f;
    const int col = j0 + (wc << 6) + rl;
    #pragma unroll
    for (int fr = 0; fr < 8; ++fr)
        #pragma unroll
        for (int q = 0; q < 4; ++q) {
            size_t rbase = ((size_t)(b0 + (wr << 7) + (fr << 4) + (qh << 2) + q) << 12) + col;
            #pragma unroll
            for (int fc = 0; fc < 4; ++fc) {
                float yv = y[rbase + (fc << 4)];
                float hv = yhat[rbase + (fc << 4)];
                float e = yv - hv;
                float wgt = 0.1f * (float)acc[fr][fc][q] + (yv != 0.0f ? 1.0f : 0.0f);
                part = fmaf(e * e, wgt, part);
            }
        }

    for (int off = 32; off; off >>= 1) part += __shfl_down(part, off, 64);
    float* red = (float*)lds;
    __syncthreads();   // drains all counters; safe to alias LDS
    if ((t & 63) == 0) red[t >> 6] = part;
    __syncthreads();
    if (t == 0) {
        float s = 0.0f;
        #pragma unroll
        for (int i = 0; i < 8; ++i) s += red[i];
        p3[swz] = (double)s;
    }
}

// ================= popcount fallback path (R8, passing) =================

__global__ __launch_bounds__(256) void k1_pack_mask(
    const float* __restrict__ y, u64* __restrict__ mbT, u64* __restrict__ pcnt)
{
    __shared__ unsigned rc[4];
    const unsigned t = threadIdx.x;
    const unsigned lane = t & 63;
    const float4* y4 = (const float4*)y;
    u64 qi = (u64)blockIdx.x * 256 + t;
    const u64 stride = (u64)2048 * 256;
    unsigned lcnt = 0;
    #pragma unroll 4
    for (int it = 0; it < 16; ++it, qi += stride) {
        float4 v = y4[qi];
        u64 b0 = __ballot(v.x != 0.0f);
        u64 b1 = __ballot(v.y != 0.0f);
        u64 b2 = __ballot(v.z != 0.0f);
        u64 b3 = __ballot(v.w != 0.0f);
        lcnt += (v.x != 0.0f) + (v.y != 0.0f) + (v.z != 0.0f) + (v.w != 0.0f);
        if (lane < 4) {
            unsigned sh = lane << 4;
            u64 word = ((b0 >> sh) & 0xFFFFull)
                     | (((b1 >> sh) & 0xFFFFull) << 16)
                     | (((b2 >> sh) & 0xFFFFull) << 32)
                     | (((b3 >> sh) & 0xFFFFull) << 48);
            u64 gw = ((qi - lane) >> 4) + lane;
            mbT[((gw & 63) << 13) + (gw >> 6)] = word;
        }
    }
    for (int off = 32; off; off >>= 1) lcnt += __shfl_down(lcnt, off, 64);
    if ((t & 63) == 0) rc[t >> 6] = lcnt;
    __syncthreads();
    if (t == 0) pcnt[blockIdx.x] = (u64)rc[0] + rc[1] + rc[2] + rc[3];
}

__global__ __launch_bounds__(256) void k2_pack_w(
    const float* __restrict__ W, u64* __restrict__ wbT)
{
    __shared__ float tile[64][65];
    const int j0 = blockIdx.x * 64;
    const int w  = blockIdx.y;
    const int i0 = w * 64;
    const int t = threadIdx.x;
    #pragma unroll
    for (int k = 0; k < 16; ++k) {
        int lin = t + (k << 8);
        int r = lin >> 6, c = lin & 63;
        tile[r][c] = W[(size_t)(i0 + r) * NS + (j0 + c)];
    }
    __syncthreads();
    const int lane = t & 63;
    const int wvv = t >> 6;
    const int pr = ((lane & 15) << 2) + (lane >> 4);
    for (int jj = wvv; jj < 64; jj += 4) {
        u64 bal = __ballot(tile[pr][jj] != 0.0f);
        if (lane == 0) wbT[((size_t)w << 12) + (j0 + jj)] = bal;
    }
}

__global__ __launch_bounds__(256) void k3_main(
    const float* __restrict__ y, const float* __restrict__ yhat,
    const u64* __restrict__ mbT, const u64* __restrict__ wbT,
    double* __restrict__ p3)
{
    __shared__ alignas(16) u64 mT[16 * 128];
    __shared__ alignas(16) u64 wT[16 * 128];
    const int b0 = blockIdx.x << 7;
    const int j0 = blockIdx.y << 7;
    const int t  = threadIdx.x;
    const int r0 = (t >> 4) << 3;
    const int cj = t & 15;
    const unsigned sx = ((unsigned)cj >> 2) << 4;

    unsigned cnt[8][8];
    #pragma unroll
    for (int a = 0; a < 8; ++a)
        #pragma unroll
        for (int b = 0; b < 8; ++b) cnt[a][b] = 0;

    char* mB = (char*)mT;
    char* wB = (char*)wT;

    #pragma unroll 1
    for (int s = 0; s < 4; ++s) {
        u64x2 gm[4], gq[4];
        #pragma unroll
        for (int k = 0; k < 4; ++k) {
            int lin = t + (k << 8);
            int wl = (s << 4) + (lin >> 6), c2 = lin & 63;
            gm[k] = *(const u64x2*)&mbT[((size_t)wl << 13) + b0 + 2 * c2];
            gq[k] = *(const u64x2*)&wbT[((size_t)wl << 12) + j0 + 2 * c2];
        }
        __syncthreads();
        #pragma unroll
        for (int k = 0; k < 4; ++k) {
            int lin = t + (k << 8);
            int wl = lin >> 6, c2 = lin & 63;
            int p = c2 ^ ((c2 >> 4) & 3);
            *(u64x2*)(mB + (wl << 10) + (c2 << 4)) = gm[k];
            *(u64x2*)(wB + (wl << 10) + (p << 4)) = gq[k];
        }
        __syncthreads();

        unsigned mo = (unsigned)(r0 << 3);
        unsigned qs = (unsigned)(cj << 6) + sx;
        #pragma unroll 2
        for (int w = 0; w < 16; ++w) {
            unsigned ml[16], ql[16];
            #pragma unroll
            for (int k = 0; k < 4; ++k) {
                uint4 a = *(const uint4*)(mB + mo + (k << 4));
                ml[4 * k + 0] = a.x; ml[4 * k + 1] = a.y;
                ml[4 * k + 2] = a.z; ml[4 * k + 3] = a.w;
                uint4 b = *(const uint4*)(wB + (qs ^ (unsigned)(k << 4)));
                ql[4 * k + 0] = b.x; ql[4 * k + 1] = b.y;
                ql[4 * k + 2] = b.z; ql[4 * k + 3] = b.w;
            }
            #pragma unroll
            for (int aa = 0; aa < 8; ++aa)
                #pragma unroll
                for (int bb = 0; bb < 8; ++bb) {
                    unsigned x0 = ml[2 * aa] & ql[2 * bb];
                    unsigned x1 = ml[2 * aa + 1] & ql[2 * bb + 1];
                    asm("v_bcnt_u32_b32 %0, %1, %0" : "+v"(cnt[aa][bb]) : "v"(x0));
                    asm("v_bcnt_u32_b32 %0, %1, %0" : "+v"(cnt[aa][bb]) : "v"(x1));
                }
            mo += 1024; qs += 1024;
        }
    }

    float part = 0.0f;
    const int c0 = cj << 3;
    #pragma unroll
    for (int aa = 0; aa < 8; ++aa) {
        size_t off = ((size_t)(b0 + r0 + aa) << 12) + (size_t)(j0 + c0);
        float ys[8], hs[8];
        *(float4*)&ys[0] = *(const float4*)(y + off);
        *(float4*)&ys[4] = *(const float4*)(y + off + 4);
        *(float4*)&hs[0] = *(const float4*)(yhat + off);
        *(float4*)&hs[4] = *(const float4*)(yhat + off + 4);
        #pragma unroll
        for (int bb = 0; bb < 8; ++bb) {
            float e = ys[bb] - hs[bb];
            float wgt = 0.1f * (float)cnt[aa][bb] + (ys[bb] != 0.0f ? 1.0f : 0.0f);
            part = fmaf(e * e, wgt, part);
        }
    }

    for (int off = 32; off; off >>= 1) part += __shfl_down(part, off, 64);
    float* red = (float*)mT;
    __syncthreads();
    if ((t & 63) == 0) red[t >> 6] = part;
    __syncthreads();
    if (t == 0)
        p3[(size_t)blockIdx.y * gridDim.x + blockIdx.x] =
            (double)red[0] + (double)red[1] + (double)red[2] + (double)red[3];
}

// ---------------- K4: final reduce + sqrt (np3 = valid p3 entries) ----------------
__global__ __launch_bounds__(256) void k4_final(
    const u64* __restrict__ pcnt, const double* __restrict__ p3, float* __restrict__ out,
    int np3)
{
    __shared__ double rs[4];
    __shared__ u64 rcc[4];
    double s3 = 0.0;
    u64 c = 0;
    for (int i = threadIdx.x; i < 2048; i += 256) c += pcnt[i];
    for (int i = threadIdx.x; i < np3; i += 256) s3 += p3[i];
    for (int off = 32; off; off >>= 1) {
        s3 += __shfl_down(s3, off, 64);
        c  += __shfl_down(c, off, 64);
    }
    int wv = threadIdx.x >> 6;
    if ((threadIdx.x & 63) == 0) { rs[wv] = s3; rcc[wv] = c; }
    __syncthreads();
    if (threadIdx.x == 0) {
        double S3 = rs[0] + rs[1] + rs[2] + rs[3];
        double C  = (double)(rcc[0] + rcc[1] + rcc[2] + rcc[3]);
        out[0] = (float)sqrt(S3 / C + 1e-6);
    }
}

extern "C" void kernel_launch(void* const* d_in, const int* in_sizes, int n_in,
                              void* d_out, int out_size, void* d_ws, size_t ws_size,
                              hipStream_t stream) {
    const float* yhat = (const float*)d_in[0];
    const float* y    = (const float*)d_in[1];
    const float* W    = (const float*)d_in[2];
    char* ws = (char*)d_ws;
    u64*    pcnt = (u64*)(ws + OFF_CNT);
    double* p3   = (double*)(ws + OFF_P3);

    if (ws_size >= WS_NEED) {
        u32* m8 = (u32*)(ws + OFF_M8);
        u32* bt = (u32*)(ws + OFF_BT);
        k12_prep<<<dim3(2048 + 4096), dim3(256), 0, stream>>>(y, W, m8, bt, pcnt);
        k3g_mfma<<<dim3(32, 16), dim3(512), 0, stream>>>(
            y, yhat, (const u8*)m8, (const u8*)bt, p3);
        k4_final<<<dim3(1), dim3(256), 0, stream>>>(pcnt, p3, (float*)d_out, 512);
    } else {
        u64* mbT = (u64*)(ws + OFF_MB);
        u64* wbT = (u64*)(ws + OFF_WB);
        k1_pack_mask<<<dim3(2048), dim3(256), 0, stream>>>(y, mbT, pcnt);
        k2_pack_w<<<dim3(64, 64), dim3(256), 0, stream>>>(W, wbT);
        k3_main<<<dim3(64, 32), dim3(256), 0, stream>>>(y, yhat, mbT, wbT, p3);
        k4_final<<<dim3(1), dim3(256), 0, stream>>>(pcnt, p3, (float*)d_out, 2048);
    }
}